// Round 1
// baseline (392.253 us; speedup 1.0000x reference)
//
#include <hip/hip_runtime.h>
#include <hip/hip_bf16.h>
#include <hip/hip_fp16.h>

typedef _Float16 f16x8 __attribute__((ext_vector_type(8)));
typedef float f32x4 __attribute__((ext_vector_type(4)));

#define T_TOK 8192
#define DIM   1024
#define FF    4096
#define NE    8
#define CAP   1024

// ---------------------------------------------------------------------------
// Router: logits = x @ Wr, softmax, top-1 (first-max tie-break), weight = prob
// One wave per token (4 tokens/wave, 16 tokens/block). Wr cached in LDS with
// row-pad 9 (gcd(9,32)=1 -> conflict-free strided reads).
// ---------------------------------------------------------------------------
__global__ __launch_bounds__(256) void moe_router(
    const float* __restrict__ x, const float* __restrict__ Wr,
    int* __restrict__ top, float* __restrict__ topw)
{
  __shared__ float sWr[DIM * 9];
  const int tid = threadIdx.x;
  for (int i = tid; i < DIM * NE; i += 256) {
    int d = i >> 3, e = i & 7;
    sWr[d * 9 + e] = Wr[i];
  }
  __syncthreads();
  const int lane = tid & 63, w = tid >> 6;
  for (int t = 0; t < 4; ++t) {
    const int token = blockIdx.x * 16 + w * 4 + t;
    float acc[8] = {0.f, 0.f, 0.f, 0.f, 0.f, 0.f, 0.f, 0.f};
    for (int j = 0; j < 16; ++j) {
      float xv = x[(size_t)token * DIM + j * 64 + lane];
      const float* wr = &sWr[(j * 64 + lane) * 9];
#pragma unroll
      for (int e = 0; e < 8; ++e) acc[e] += xv * wr[e];
    }
#pragma unroll
    for (int e = 0; e < 8; ++e) {
#pragma unroll
      for (int off = 32; off > 0; off >>= 1)
        acc[e] += __shfl_xor(acc[e], off, 64);
    }
    if (lane == 0) {
      float m = acc[0];
#pragma unroll
      for (int e = 1; e < 8; ++e) m = fmaxf(m, acc[e]);
      float s = 0.f;
#pragma unroll
      for (int e = 0; e < 8; ++e) s += expf(acc[e] - m);
      int bi = 0; float bv = acc[0];
#pragma unroll
      for (int e = 1; e < 8; ++e) { if (acc[e] > bv) { bv = acc[e]; bi = e; } }
      top[token]  = bi;
      topw[token] = 1.0f / s;   // softmax prob of the (arg)max logit
    }
  }
}

// ---------------------------------------------------------------------------
// Order-preserving dispatch: stable per-expert compaction (first CAP tokens in
// token order, fill = T). Single block, 32 chunks of 256 tokens, ballot ranks.
// ---------------------------------------------------------------------------
__global__ __launch_bounds__(256) void moe_scan(
    const int* __restrict__ top, int* __restrict__ idx)
{
  __shared__ int running[8];
  __shared__ int wcnt[4][8];
  __shared__ int wpre[4][8];
  __shared__ int cbase[8];
  const int tid = threadIdx.x, lane = tid & 63, w = tid >> 6;
  for (int i = tid; i < NE * CAP; i += 256) idx[i] = T_TOK;  // fill value
  if (tid < 8) running[tid] = 0;
  __syncthreads();
  for (int chunk = 0; chunk < T_TOK / 256; ++chunk) {
    const int tok = chunk * 256 + tid;
    const int e = top[tok];
    unsigned long long mymask = 0ull;
#pragma unroll
    for (int ee = 0; ee < 8; ++ee) {
      unsigned long long m = __ballot(e == ee);
      if (ee == e) mymask = m;
      if (lane == ee) wcnt[w][ee] = __builtin_popcountll(m);
    }
    const int rankw = __builtin_popcountll(mymask & ((1ull << lane) - 1ull));
    __syncthreads();
    if (tid < 8) {
      int c0 = wcnt[0][tid], c1 = wcnt[1][tid], c2 = wcnt[2][tid], c3 = wcnt[3][tid];
      wpre[0][tid] = 0; wpre[1][tid] = c0; wpre[2][tid] = c0 + c1; wpre[3][tid] = c0 + c1 + c2;
      cbase[tid] = running[tid];
      running[tid] += c0 + c1 + c2 + c3;
    }
    __syncthreads();
    const int rank = cbase[e] + wpre[w][e] + rankw;
    if (rank < CAP) idx[e * CAP + rank] = tok;
  }
}

// ---------------------------------------------------------------------------
// GEMM1: hidden = relu(gather(x) @ W1[e] + b1[e])  -> fp16, stored in the
// pre-swizzled 16KB-tile image layout that GEMM2's A-staging copies linearly.
// 128x128 tile, BK=64, 4 waves (2x2), mfma_f32_16x16x32_f16.
// LDS swizzle: granule (8 f16) index g stored at g ^ (row&7).
// ---------------------------------------------------------------------------
__global__ __launch_bounds__(256, 2) void moe_gemm1(
    const float* __restrict__ x, const float* __restrict__ W1,
    const float* __restrict__ b1, const int* __restrict__ idx,
    _Float16* __restrict__ hidden)
{
  __shared__ alignas(16) _Float16 As[128 * 64];
  __shared__ alignas(16) _Float16 Bs[128 * 64];
  const int tid = threadIdx.x;
  const int lane = tid & 63;
  const int w = tid >> 6;
  const int wm = w >> 1, wn = w & 1;
  const int bid = blockIdx.x;
  const int nt = bid & 31;          // F tile (32)
  const int mt = (bid >> 5) & 7;    // row tile (8)
  const int e  = bid >> 8;          // expert

  // A gather: each thread owns one tile row (arow) and one k-half
  const int arow  = tid & 127;
  const int ahalf = tid >> 7;
  const int tok   = idx[e * CAP + mt * 128 + arow];
  const bool av   = tok < T_TOK;
  const float* aptr = x + (size_t)(av ? tok : 0) * DIM + ahalf * 32;

  // B transpose-stage: thread covers 4 cols (n) x 8 k-rows
  const int bc = tid & 31, br = tid >> 5;
  const int bn0 = bc * 4;
  const float* bptr = W1 + (size_t)e * DIM * FF + (size_t)(br * 8) * FF + nt * 128 + bn0;

  const f32x4 vzero = {0.f, 0.f, 0.f, 0.f};
  f32x4 acc[4][4];
#pragma unroll
  for (int i = 0; i < 4; i++)
#pragma unroll
    for (int j = 0; j < 4; j++) acc[i][j] = vzero;

  for (int kt = 0; kt < DIM / 64; ++kt) {
    __syncthreads();
    { // stage A (fp32 -> fp16, swizzled)
      f32x4 v[8];
      if (av) {
        const f32x4* src = (const f32x4*)(aptr + kt * 64);
#pragma unroll
        for (int i = 0; i < 8; i++) v[i] = src[i];
      } else {
#pragma unroll
        for (int i = 0; i < 8; i++) v[i] = vzero;
      }
#pragma unroll
      for (int j = 0; j < 4; j++) {
        f16x8 g;
#pragma unroll
        for (int c = 0; c < 4; c++) {
          g[c]     = (_Float16)v[2 * j][c];
          g[4 + c] = (_Float16)v[2 * j + 1][c];
        }
        const int gi = (ahalf * 4 + j) ^ (arow & 7);
        *(f16x8*)&As[arow * 64 + gi * 8] = g;
      }
    }
    { // stage B (register transpose fp32 [k][n] -> fp16 Bs[n][k], swizzled)
      const float* src = bptr + (size_t)kt * 64 * FF;
      f32x4 u[8];
#pragma unroll
      for (int r = 0; r < 8; r++) u[r] = *(const f32x4*)(src + (size_t)r * FF);
#pragma unroll
      for (int c = 0; c < 4; c++) {
        f16x8 h;
#pragma unroll
        for (int r = 0; r < 8; r++) h[r] = (_Float16)u[r][c];
        const int n  = bn0 + c;
        const int gi = br ^ (n & 7);
        *(f16x8*)&Bs[n * 64 + gi * 8] = h;
      }
    }
    __syncthreads();
    // compute: 2 k-slices of 32, 16 MFMA each
#pragma unroll
    for (int ks = 0; ks < 2; ++ks) {
      const int gq = ks * 4 + (lane >> 4);
      f16x8 af[4], bf[4];
#pragma unroll
      for (int fm = 0; fm < 4; ++fm) {
        const int m = wm * 64 + fm * 16 + (lane & 15);
        af[fm] = *(const f16x8*)&As[m * 64 + (gq ^ (m & 7)) * 8];
      }
#pragma unroll
      for (int fn = 0; fn < 4; ++fn) {
        const int n = wn * 64 + fn * 16 + (lane & 15);
        bf[fn] = *(const f16x8*)&Bs[n * 64 + (gq ^ (n & 7)) * 8];
      }
#pragma unroll
      for (int fm = 0; fm < 4; ++fm)
#pragma unroll
        for (int fn = 0; fn < 4; ++fn)
          acc[fm][fn] = __builtin_amdgcn_mfma_f32_16x16x32_f16(af[fm], bf[fn], acc[fm][fn], 0, 0, 0);
    }
  }
  // epilogue: relu(acc + b1) -> hidden image tile (e, mt, f>>6), swizzled
#pragma unroll
  for (int fn = 0; fn < 4; ++fn) {
    const int f  = nt * 128 + wn * 64 + fn * 16 + (lane & 15);
    const float bb = b1[e * FF + f];
    const int fo = f & 63;
    const size_t base = ((size_t)(e * 8 + mt) * 64 + (f >> 6)) * 8192;
#pragma unroll
    for (int fm = 0; fm < 4; ++fm) {
      const int m0 = wm * 64 + fm * 16 + ((lane >> 4) << 2);
#pragma unroll
      for (int r = 0; r < 4; r++) {
        const int m = m0 + r;
        const float vv = fmaxf(acc[fm][fn][r] + bb, 0.f);
        hidden[base + (size_t)m * 64 + ((((fo >> 3) ^ (m & 7)) << 3) + (fo & 7))] = (_Float16)vv;
      }
    }
  }
}

// ---------------------------------------------------------------------------
// GEMM2: out[token] = (hidden @ W2[e] + b2[e]) * topw[token], scattered.
// A-staging = linear 16KB copy of the pre-swizzled image (fp16, no convert).
// ---------------------------------------------------------------------------
__global__ __launch_bounds__(256, 2) void moe_gemm2(
    const _Float16* __restrict__ hidden, const float* __restrict__ W2,
    const float* __restrict__ b2, const int* __restrict__ idx,
    const float* __restrict__ topw, float* __restrict__ out)
{
  __shared__ alignas(16) _Float16 As[128 * 64];
  __shared__ alignas(16) _Float16 Bs[128 * 64];
  const int tid = threadIdx.x;
  const int lane = tid & 63;
  const int w = tid >> 6;
  const int wm = w >> 1, wn = w & 1;
  const int bid = blockIdx.x;
  const int nt = bid & 7;           // D tile (8)
  const int mt = (bid >> 3) & 7;    // row tile (8)
  const int e  = bid >> 6;          // expert

  const int bc = tid & 31, br = tid >> 5;
  const int bn0 = bc * 4;
  const float* bptr = W2 + (size_t)e * FF * DIM + (size_t)(br * 8) * DIM + nt * 128 + bn0;
  const _Float16* atile = hidden + (size_t)(e * 8 + mt) * 64 * 8192;

  const f32x4 vzero = {0.f, 0.f, 0.f, 0.f};
  f32x4 acc[4][4];
#pragma unroll
  for (int i = 0; i < 4; i++)
#pragma unroll
    for (int j = 0; j < 4; j++) acc[i][j] = vzero;

  for (int kt = 0; kt < FF / 64; ++kt) {
    __syncthreads();
    { // stage A: linear copy of pre-swizzled 16KB image tile
      const f16x8* src = (const f16x8*)(atile + (size_t)kt * 8192);
#pragma unroll
      for (int p = 0; p < 4; p++)
        *(f16x8*)&As[(p * 256 + tid) * 8] = src[p * 256 + tid];
    }
    { // stage B (register transpose fp32 -> fp16)
      const float* src = bptr + (size_t)kt * 64 * DIM;
      f32x4 u[8];
#pragma unroll
      for (int r = 0; r < 8; r++) u[r] = *(const f32x4*)(src + (size_t)r * DIM);
#pragma unroll
      for (int c = 0; c < 4; c++) {
        f16x8 h;
#pragma unroll
        for (int r = 0; r < 8; r++) h[r] = (_Float16)u[r][c];
        const int n  = bn0 + c;
        const int gi = br ^ (n & 7);
        *(f16x8*)&Bs[n * 64 + gi * 8] = h;
      }
    }
    __syncthreads();
#pragma unroll
    for (int ks = 0; ks < 2; ++ks) {
      const int gq = ks * 4 + (lane >> 4);
      f16x8 af[4], bf[4];
#pragma unroll
      for (int fm = 0; fm < 4; ++fm) {
        const int m = wm * 64 + fm * 16 + (lane & 15);
        af[fm] = *(const f16x8*)&As[m * 64 + (gq ^ (m & 7)) * 8];
      }
#pragma unroll
      for (int fn = 0; fn < 4; ++fn) {
        const int n = wn * 64 + fn * 16 + (lane & 15);
        bf[fn] = *(const f16x8*)&Bs[n * 64 + (gq ^ (n & 7)) * 8];
      }
#pragma unroll
      for (int fm = 0; fm < 4; ++fm)
#pragma unroll
        for (int fn = 0; fn < 4; ++fn)
          acc[fm][fn] = __builtin_amdgcn_mfma_f32_16x16x32_f16(af[fm], bf[fn], acc[fm][fn], 0, 0, 0);
    }
  }
  // epilogue: scatter (acc + b2) * topw to out rows; skip fill slots
  int   toks[4][4];
  float wgts[4][4];
#pragma unroll
  for (int fm = 0; fm < 4; ++fm)
#pragma unroll
    for (int r = 0; r < 4; r++) {
      const int row = mt * 128 + wm * 64 + fm * 16 + ((lane >> 4) << 2) + r;
      const int tk = idx[e * CAP + row];
      toks[fm][r] = tk;
      wgts[fm][r] = (tk < T_TOK) ? topw[tk] : 0.f;
    }
#pragma unroll
  for (int fn = 0; fn < 4; ++fn) {
    const int dcol = nt * 128 + wn * 64 + fn * 16 + (lane & 15);
    const float bb = b2[e * DIM + dcol];
#pragma unroll
    for (int fm = 0; fm < 4; ++fm)
#pragma unroll
      for (int r = 0; r < 4; r++) {
        const int tk = toks[fm][r];
        if (tk < T_TOK)
          out[(size_t)tk * DIM + dcol] = (acc[fm][fn][r] + bb) * wgts[fm][r];
      }
  }
}

// ---------------------------------------------------------------------------
extern "C" void kernel_launch(void* const* d_in, const int* in_sizes, int n_in,
                              void* d_out, int out_size, void* d_ws, size_t ws_size,
                              hipStream_t stream)
{
  const float* x  = (const float*)d_in[0];
  const float* Wr = (const float*)d_in[1];
  const float* W1 = (const float*)d_in[2];
  const float* b1 = (const float*)d_in[3];
  const float* W2 = (const float*)d_in[4];
  const float* b2 = (const float*)d_in[5];
  float* out = (float*)d_out;
  char* ws = (char*)d_ws;

  _Float16* hidden = (_Float16*)ws;                       // 67,108,864 B (fp16 image)
  const size_t HID_BYTES = (size_t)NE * CAP * FF * 2;
  int*   idx  = (int*)(ws + HID_BYTES);                   // 32 KB
  int*   top  = (int*)(ws + HID_BYTES + 32768);           // 32 KB
  float* topw = (float*)(ws + HID_BYTES + 65536);         // 32 KB

  hipMemsetAsync(d_out, 0, (size_t)T_TOK * DIM * sizeof(float), stream);
  moe_router<<<T_TOK / 16, 256, 0, stream>>>(x, Wr, top, topw);
  moe_scan<<<1, 256, 0, stream>>>(top, idx);
  moe_gemm1<<<NE * 8 * 32, 256, 0, stream>>>(x, W1, b1, idx, hidden);
  moe_gemm2<<<NE * 8 * 8, 256, 0, stream>>>(hidden, W2, b2, idx, topw, out);
}

// Round 2
// 359.102 us; speedup vs baseline: 1.0923x; 1.0923x over previous
//
#include <hip/hip_runtime.h>
#include <hip/hip_bf16.h>
#include <hip/hip_fp16.h>

typedef _Float16 f16x8 __attribute__((ext_vector_type(8)));
typedef _Float16 f16x4 __attribute__((ext_vector_type(4)));
typedef _Float16 f16x2 __attribute__((ext_vector_type(2)));
typedef float f32x4 __attribute__((ext_vector_type(4)));

#define T_TOK 8192
#define DIM   1024
#define FF    4096
#define NE    8
#define CAP   1024

// ---------------------------------------------------------------------------
// async global->LDS 16B copy. LDS dest = wave-uniform base + lane*16 (HW);
// global src is per-lane.
// ---------------------------------------------------------------------------
__device__ __forceinline__ void cp16(_Float16* lds, const _Float16* g) {
  __builtin_amdgcn_global_load_lds(
      (const __attribute__((address_space(1))) unsigned int*)(const void*)g,
      (__attribute__((address_space(3))) unsigned int*)(void*)lds, 16, 0, 0);
}

// ---------------------------------------------------------------------------
// Router (unchanged, proven): logits = x @ Wr, softmax, top-1, weight = prob
// ---------------------------------------------------------------------------
__global__ __launch_bounds__(256) void moe_router(
    const float* __restrict__ x, const float* __restrict__ Wr,
    int* __restrict__ top, float* __restrict__ topw)
{
  __shared__ float sWr[DIM * 9];
  const int tid = threadIdx.x;
  for (int i = tid; i < DIM * NE; i += 256) {
    int d = i >> 3, e = i & 7;
    sWr[d * 9 + e] = Wr[i];
  }
  __syncthreads();
  const int lane = tid & 63, w = tid >> 6;
  for (int t = 0; t < 4; ++t) {
    const int token = blockIdx.x * 16 + w * 4 + t;
    float acc[8] = {0.f, 0.f, 0.f, 0.f, 0.f, 0.f, 0.f, 0.f};
    for (int j = 0; j < 16; ++j) {
      float xv = x[(size_t)token * DIM + j * 64 + lane];
      const float* wr = &sWr[(j * 64 + lane) * 9];
#pragma unroll
      for (int e = 0; e < 8; ++e) acc[e] += xv * wr[e];
    }
#pragma unroll
    for (int e = 0; e < 8; ++e) {
#pragma unroll
      for (int off = 32; off > 0; off >>= 1)
        acc[e] += __shfl_xor(acc[e], off, 64);
    }
    if (lane == 0) {
      float m = acc[0];
#pragma unroll
      for (int e = 1; e < 8; ++e) m = fmaxf(m, acc[e]);
      float s = 0.f;
#pragma unroll
      for (int e = 0; e < 8; ++e) s += expf(acc[e] - m);
      int bi = 0; float bv = acc[0];
#pragma unroll
      for (int e = 1; e < 8; ++e) { if (acc[e] > bv) { bv = acc[e]; bi = e; } }
      top[token]  = bi;
      topw[token] = 1.0f / s;
    }
  }
}

// ---------------------------------------------------------------------------
// Order-preserving dispatch (unchanged, proven)
// ---------------------------------------------------------------------------
__global__ __launch_bounds__(256) void moe_scan(
    const int* __restrict__ top, int* __restrict__ idx)
{
  __shared__ int running[8];
  __shared__ int wcnt[4][8];
  __shared__ int wpre[4][8];
  __shared__ int cbase[8];
  const int tid = threadIdx.x, lane = tid & 63, w = tid >> 6;
  for (int i = tid; i < NE * CAP; i += 256) idx[i] = T_TOK;
  if (tid < 8) running[tid] = 0;
  __syncthreads();
  for (int chunk = 0; chunk < T_TOK / 256; ++chunk) {
    const int tok = chunk * 256 + tid;
    const int e = top[tok];
    unsigned long long mymask = 0ull;
#pragma unroll
    for (int ee = 0; ee < 8; ++ee) {
      unsigned long long m = __ballot(e == ee);
      if (ee == e) mymask = m;
      if (lane == ee) wcnt[w][ee] = __builtin_popcountll(m);
    }
    const int rankw = __builtin_popcountll(mymask & ((1ull << lane) - 1ull));
    __syncthreads();
    if (tid < 8) {
      int c0 = wcnt[0][tid], c1 = wcnt[1][tid], c2 = wcnt[2][tid], c3 = wcnt[3][tid];
      wpre[0][tid] = 0; wpre[1][tid] = c0; wpre[2][tid] = c0 + c1; wpre[3][tid] = c0 + c1 + c2;
      cbase[tid] = running[tid];
      running[tid] += c0 + c1 + c2 + c3;
    }
    __syncthreads();
    const int rank = cbase[e] + wpre[w][e] + rankw;
    if (rank < CAP) idx[e * CAP + rank] = tok;
  }
}

// ---------------------------------------------------------------------------
// Gathered-x fp16 image: tiles [e][mt 4][kt 16] of [256 rows][8 granules],
// granule g stored at position g ^ (row&7). OOB rows -> zeros.
// ---------------------------------------------------------------------------
__global__ __launch_bounds__(256) void xg_pass(
    const float* __restrict__ x, const int* __restrict__ idx,
    _Float16* __restrict__ img)
{
  const int tid = threadIdx.x, bid = blockIdx.x;
  const int kt = bid & 15, mt = (bid >> 4) & 3, e = bid >> 6;
  const int tok = idx[e * CAP + mt * 256 + tid];
  _Float16* dst = img + (size_t)((e * 4 + mt) * 16 + kt) * 16384 + (size_t)tid * 64;
  if (tok < T_TOK) {
    const f32x4* src = (const f32x4*)(x + (size_t)tok * DIM + kt * 64);
    f32x4 v[16];
#pragma unroll
    for (int i = 0; i < 16; ++i) v[i] = src[i];
#pragma unroll
    for (int g = 0; g < 8; ++g) {
      f16x8 h;
#pragma unroll
      for (int c = 0; c < 4; ++c) {
        h[c]     = (_Float16)v[2 * g][c];
        h[4 + c] = (_Float16)v[2 * g + 1][c];
      }
      *(f16x8*)(dst + ((g ^ (tid & 7)) * 8)) = h;
    }
  } else {
    f16x8 z = {};
#pragma unroll
    for (int g = 0; g < 8; ++g) *(f16x8*)(dst + g * 8) = z;
  }
}

// ---------------------------------------------------------------------------
// W fp32 [K][N] -> fp16 image tiles [n BN][k 64] with granule swizzle
// g stored at g ^ (n&7). LDS-bounce transpose; column reads are 2-way-free
// (row stride 512B/256B is bank-aligned, bank = (n>>1)&31, n per-lane).
// ---------------------------------------------------------------------------
template<int BN, int NKT, int NNT, int NFULL>
__global__ __launch_bounds__(256) void w_image(
    const float* __restrict__ W, _Float16* __restrict__ img)
{
  __shared__ _Float16 sT[64 * BN];
  const int tid = threadIdx.x, bid = blockIdx.x;
  const int kt = bid % NKT, nt = (bid / NKT) % NNT, e = bid / (NKT * NNT);
  const float* src = W + (size_t)e * (NKT * 64) * NFULL + (size_t)(kt * 64) * NFULL + nt * BN;
  constexpr int CPT = (64 * BN / 4) / 256;
#pragma unroll
  for (int i = 0; i < CPT; ++i) {
    const int q = i * 256 + tid;
    const int row = q / (BN / 4), c4 = q % (BN / 4);
    f32x4 u = *(const f32x4*)(src + (size_t)row * NFULL + c4 * 4);
    f16x4 h;
#pragma unroll
    for (int c = 0; c < 4; ++c) h[c] = (_Float16)u[c];
    *(f16x4*)&sT[row * BN + c4 * 4] = h;
  }
  __syncthreads();
  _Float16* dst = img + (size_t)bid * (BN * 64);
  constexpr int GPT = BN * 8 / 256;
  const int n = tid % BN, gb = (tid / BN) * GPT;
#pragma unroll
  for (int i = 0; i < GPT; ++i) {
    const int gpos = gb + i, g = gpos ^ (n & 7);
    f16x8 h;
#pragma unroll
    for (int j = 0; j < 8; ++j) h[j] = sT[(g * 8 + j) * BN + n];
    *(f16x8*)(dst + (size_t)n * 64 + gpos * 8) = h;
  }
}

// ---------------------------------------------------------------------------
// GEMM1: hidden = relu(xg @ W1img + b1). 256x256xBK64, 512 thr (8 waves 2x4),
// double-buffered LDS (128 KB), single barrier/K-step, all-gload_lds staging.
// Epilogue writes hidden image tiles [e][mt][kt' 64][256][8 granules swz].
// ---------------------------------------------------------------------------
__global__ __launch_bounds__(512, 2) void gemm1_big(
    const _Float16* __restrict__ xg, const _Float16* __restrict__ w1img,
    const float* __restrict__ b1, _Float16* __restrict__ hidden)
{
  __shared__ _Float16 As[2][16384];
  __shared__ _Float16 Bs[2][16384];
  const int tid = threadIdx.x, lane = tid & 63, w = tid >> 6;
  const int wm = w >> 2, wn = w & 3;
  const int l15 = lane & 15, l4 = lane >> 4;
  const int bid = blockIdx.x;
  const int nt = bid & 15, mt = (bid >> 4) & 3, e = bid >> 6;

  const _Float16* aSrc = xg    + (size_t)((e * 4 + mt) * 16) * 16384 + w * 2048 + lane * 8;
  const _Float16* bSrc = w1img + (size_t)((e * 16 + nt) * 16) * 16384 + w * 2048 + lane * 8;

  f32x4 acc[8][4];
#pragma unroll
  for (int i = 0; i < 8; ++i)
#pragma unroll
    for (int j = 0; j < 4; ++j) acc[i][j] = (f32x4){0.f, 0.f, 0.f, 0.f};

#pragma unroll
  for (int i = 0; i < 4; ++i) {
    cp16(&As[0][w * 2048 + i * 512], aSrc + i * 512);
    cp16(&Bs[0][w * 2048 + i * 512], bSrc + i * 512);
  }
  __syncthreads();

  for (int kt = 0; kt < 16; ++kt) {
    const int c = kt & 1;
    if (kt < 15) {
#pragma unroll
      for (int i = 0; i < 4; ++i) {
        cp16(&As[c ^ 1][w * 2048 + i * 512], aSrc + (size_t)(kt + 1) * 16384 + i * 512);
        cp16(&Bs[c ^ 1][w * 2048 + i * 512], bSrc + (size_t)(kt + 1) * 16384 + i * 512);
      }
    }
#pragma unroll
    for (int ks = 0; ks < 2; ++ks) {
      const int gsw = ((ks * 4 + l4) ^ (l15 & 7)) * 8;
      f16x8 bf[4];
#pragma unroll
      for (int fn = 0; fn < 4; ++fn)
        bf[fn] = *(const f16x8*)&Bs[c][(wn * 64 + fn * 16 + l15) * 64 + gsw];
#pragma unroll
      for (int fm = 0; fm < 8; ++fm) {
        f16x8 af = *(const f16x8*)&As[c][(wm * 128 + fm * 16 + l15) * 64 + gsw];
#pragma unroll
        for (int fn = 0; fn < 4; ++fn)
          acc[fm][fn] = __builtin_amdgcn_mfma_f32_16x16x32_f16(af, bf[fn], acc[fm][fn], 0, 0, 0);
      }
    }
    __syncthreads();
  }

  // epilogue: relu(acc+b1) -> hidden image, pair-packed 4B stores (even lanes)
  const size_t tb0 = (size_t)((e * 4 + mt) * 64 + nt * 4) * 16384;
#pragma unroll
  for (int fn = 0; fn < 4; ++fn) {
    const int fl = wn * 64 + fn * 16 + l15;
    const float bb = b1[e * FF + nt * 256 + fl];
    const size_t tb = tb0 + (size_t)(fl >> 6) * 16384;
    const int gph = (fl >> 3) & 7, j0 = fl & 7;
#pragma unroll
    for (int fm = 0; fm < 8; ++fm) {
#pragma unroll
      for (int r = 0; r < 4; ++r) {
        const int m = wm * 128 + fm * 16 + l4 * 4 + r;
        float v = fmaxf(acc[fm][fn][r] + bb, 0.f);
        float o = __shfl_xor(v, 1);
        if ((lane & 1) == 0) {
          f16x2 p; p[0] = (_Float16)v; p[1] = (_Float16)o;
          *(f16x2*)&hidden[tb + (size_t)m * 64 + (gph ^ (m & 7)) * 8 + j0] = p;
        }
      }
    }
  }
}

// ---------------------------------------------------------------------------
// GEMM2: out[tok] = (hidden @ W2img + b2) * topw. 256x128xBK64, 512 thr
// (8 waves 4x2), dbuf LDS (96 KB), single barrier/K-step, all-gload_lds.
// ---------------------------------------------------------------------------
__global__ __launch_bounds__(512, 2) void gemm2_big(
    const _Float16* __restrict__ hidden, const _Float16* __restrict__ w2img,
    const float* __restrict__ b2, const int* __restrict__ idx,
    const float* __restrict__ topw, float* __restrict__ out)
{
  __shared__ _Float16 As[2][16384];
  __shared__ _Float16 Bs[2][8192];
  const int tid = threadIdx.x, lane = tid & 63, w = tid >> 6;
  const int wm = w >> 1, wn = w & 1;
  const int l15 = lane & 15, l4 = lane >> 4;
  const int bid = blockIdx.x;
  const int nt = bid & 7, mt = (bid >> 3) & 3, e = bid >> 5;

  const _Float16* aSrc = hidden + (size_t)((e * 4 + mt) * 64) * 16384 + w * 2048 + lane * 8;
  const _Float16* bSrc = w2img  + (size_t)((e * 8 + nt) * 64) * 8192 + w * 1024 + lane * 8;

  f32x4 acc[4][4];
#pragma unroll
  for (int i = 0; i < 4; ++i)
#pragma unroll
    for (int j = 0; j < 4; ++j) acc[i][j] = (f32x4){0.f, 0.f, 0.f, 0.f};

#pragma unroll
  for (int i = 0; i < 4; ++i) cp16(&As[0][w * 2048 + i * 512], aSrc + i * 512);
#pragma unroll
  for (int i = 0; i < 2; ++i) cp16(&Bs[0][w * 1024 + i * 512], bSrc + i * 512);
  __syncthreads();

  for (int kt = 0; kt < 64; ++kt) {
    const int c = kt & 1;
    if (kt < 63) {
#pragma unroll
      for (int i = 0; i < 4; ++i)
        cp16(&As[c ^ 1][w * 2048 + i * 512], aSrc + (size_t)(kt + 1) * 16384 + i * 512);
#pragma unroll
      for (int i = 0; i < 2; ++i)
        cp16(&Bs[c ^ 1][w * 1024 + i * 512], bSrc + (size_t)(kt + 1) * 8192 + i * 512);
    }
#pragma unroll
    for (int ks = 0; ks < 2; ++ks) {
      const int gsw = ((ks * 4 + l4) ^ (l15 & 7)) * 8;
      f16x8 bf[4];
#pragma unroll
      for (int fn = 0; fn < 4; ++fn)
        bf[fn] = *(const f16x8*)&Bs[c][(wn * 64 + fn * 16 + l15) * 64 + gsw];
#pragma unroll
      for (int fm = 0; fm < 4; ++fm) {
        f16x8 af = *(const f16x8*)&As[c][(wm * 64 + fm * 16 + l15) * 64 + gsw];
#pragma unroll
        for (int fn = 0; fn < 4; ++fn)
          acc[fm][fn] = __builtin_amdgcn_mfma_f32_16x16x32_f16(af, bf[fn], acc[fm][fn], 0, 0, 0);
      }
    }
    __syncthreads();
  }

  // epilogue: scatter (acc + b2) * topw to token rows
  int   toks[4][4];
  float wgts[4][4];
#pragma unroll
  for (int fm = 0; fm < 4; ++fm)
#pragma unroll
    for (int r = 0; r < 4; ++r) {
      const int cr = mt * 256 + wm * 64 + fm * 16 + l4 * 4 + r;
      const int tk = idx[e * CAP + cr];
      toks[fm][r] = tk;
      wgts[fm][r] = (tk < T_TOK) ? topw[tk] : 0.f;
    }
#pragma unroll
  for (int fn = 0; fn < 4; ++fn) {
    const int dcol = nt * 128 + wn * 64 + fn * 16 + l15;
    const float bb = b2[e * DIM + dcol];
#pragma unroll
    for (int fm = 0; fm < 4; ++fm)
#pragma unroll
      for (int r = 0; r < 4; ++r) {
        const int tk = toks[fm][r];
        if (tk < T_TOK)
          out[(size_t)tk * DIM + dcol] = (acc[fm][fn][r] + bb) * wgts[fm][r];
      }
  }
}

// ===========================================================================
// Round-1 fallback kernels (proven) — used when ws_size is too small for the
// image pipeline.
// ===========================================================================
__global__ __launch_bounds__(256, 2) void moe_gemm1(
    const float* __restrict__ x, const float* __restrict__ W1,
    const float* __restrict__ b1, const int* __restrict__ idx,
    _Float16* __restrict__ hidden)
{
  __shared__ alignas(16) _Float16 As[128 * 64];
  __shared__ alignas(16) _Float16 Bs[128 * 64];
  const int tid = threadIdx.x;
  const int lane = tid & 63;
  const int w = tid >> 6;
  const int wm = w >> 1, wn = w & 1;
  const int bid = blockIdx.x;
  const int nt = bid & 31;
  const int mt = (bid >> 5) & 7;
  const int e  = bid >> 8;

  const int arow  = tid & 127;
  const int ahalf = tid >> 7;
  const int tok   = idx[e * CAP + mt * 128 + arow];
  const bool av   = tok < T_TOK;
  const float* aptr = x + (size_t)(av ? tok : 0) * DIM + ahalf * 32;

  const int bc = tid & 31, br = tid >> 5;
  const int bn0 = bc * 4;
  const float* bptr = W1 + (size_t)e * DIM * FF + (size_t)(br * 8) * FF + nt * 128 + bn0;

  const f32x4 vzero = {0.f, 0.f, 0.f, 0.f};
  f32x4 acc[4][4];
#pragma unroll
  for (int i = 0; i < 4; i++)
#pragma unroll
    for (int j = 0; j < 4; j++) acc[i][j] = vzero;

  for (int kt = 0; kt < DIM / 64; ++kt) {
    __syncthreads();
    {
      f32x4 v[8];
      if (av) {
        const f32x4* src = (const f32x4*)(aptr + kt * 64);
#pragma unroll
        for (int i = 0; i < 8; i++) v[i] = src[i];
      } else {
#pragma unroll
        for (int i = 0; i < 8; i++) v[i] = vzero;
      }
#pragma unroll
      for (int j = 0; j < 4; j++) {
        f16x8 g;
#pragma unroll
        for (int c = 0; c < 4; c++) {
          g[c]     = (_Float16)v[2 * j][c];
          g[4 + c] = (_Float16)v[2 * j + 1][c];
        }
        const int gi = (ahalf * 4 + j) ^ (arow & 7);
        *(f16x8*)&As[arow * 64 + gi * 8] = g;
      }
    }
    {
      const float* src = bptr + (size_t)kt * 64 * FF;
      f32x4 u[8];
#pragma unroll
      for (int r = 0; r < 8; r++) u[r] = *(const f32x4*)(src + (size_t)r * FF);
#pragma unroll
      for (int c = 0; c < 4; c++) {
        f16x8 h;
#pragma unroll
        for (int r = 0; r < 8; r++) h[r] = (_Float16)u[r][c];
        const int n  = bn0 + c;
        const int gi = br ^ (n & 7);
        *(f16x8*)&Bs[n * 64 + gi * 8] = h;
      }
    }
    __syncthreads();
#pragma unroll
    for (int ks = 0; ks < 2; ++ks) {
      const int gq = ks * 4 + (lane >> 4);
      f16x8 af[4], bf[4];
#pragma unroll
      for (int fm = 0; fm < 4; ++fm) {
        const int m = wm * 64 + fm * 16 + (lane & 15);
        af[fm] = *(const f16x8*)&As[m * 64 + (gq ^ (m & 7)) * 8];
      }
#pragma unroll
      for (int fn = 0; fn < 4; ++fn) {
        const int n = wn * 64 + fn * 16 + (lane & 15);
        bf[fn] = *(const f16x8*)&Bs[n * 64 + (gq ^ (n & 7)) * 8];
      }
#pragma unroll
      for (int fm = 0; fm < 4; ++fm)
#pragma unroll
        for (int fn = 0; fn < 4; ++fn)
          acc[fm][fn] = __builtin_amdgcn_mfma_f32_16x16x32_f16(af[fm], bf[fn], acc[fm][fn], 0, 0, 0);
    }
  }
#pragma unroll
  for (int fn = 0; fn < 4; ++fn) {
    const int f  = nt * 128 + wn * 64 + fn * 16 + (lane & 15);
    const float bb = b1[e * FF + f];
    const int fo = f & 63;
    const size_t base = ((size_t)(e * 8 + mt) * 64 + (f >> 6)) * 8192;
#pragma unroll
    for (int fm = 0; fm < 4; ++fm) {
      const int m0 = wm * 64 + fm * 16 + ((lane >> 4) << 2);
#pragma unroll
      for (int r = 0; r < 4; r++) {
        const int m = m0 + r;
        const float vv = fmaxf(acc[fm][fn][r] + bb, 0.f);
        hidden[base + (size_t)m * 64 + ((((fo >> 3) ^ (m & 7)) << 3) + (fo & 7))] = (_Float16)vv;
      }
    }
  }
}

__global__ __launch_bounds__(256, 2) void moe_gemm2(
    const _Float16* __restrict__ hidden, const float* __restrict__ W2,
    const float* __restrict__ b2, const int* __restrict__ idx,
    const float* __restrict__ topw, float* __restrict__ out)
{
  __shared__ alignas(16) _Float16 As[128 * 64];
  __shared__ alignas(16) _Float16 Bs[128 * 64];
  const int tid = threadIdx.x;
  const int lane = tid & 63;
  const int w = tid >> 6;
  const int wm = w >> 1, wn = w & 1;
  const int bid = blockIdx.x;
  const int nt = bid & 7;
  const int mt = (bid >> 3) & 7;
  const int e  = bid >> 6;

  const int bc = tid & 31, br = tid >> 5;
  const int bn0 = bc * 4;
  const float* bptr = W2 + (size_t)e * FF * DIM + (size_t)(br * 8) * DIM + nt * 128 + bn0;
  const _Float16* atile = hidden + (size_t)(e * 8 + mt) * 64 * 8192;

  const f32x4 vzero = {0.f, 0.f, 0.f, 0.f};
  f32x4 acc[4][4];
#pragma unroll
  for (int i = 0; i < 4; i++)
#pragma unroll
    for (int j = 0; j < 4; j++) acc[i][j] = vzero;

  for (int kt = 0; kt < FF / 64; ++kt) {
    __syncthreads();
    {
      const f16x8* src = (const f16x8*)(atile + (size_t)kt * 8192);
#pragma unroll
      for (int p = 0; p < 4; p++)
        *(f16x8*)&As[(p * 256 + tid) * 8] = src[p * 256 + tid];
    }
    {
      const float* src = bptr + (size_t)kt * 64 * DIM;
      f32x4 u[8];
#pragma unroll
      for (int r = 0; r < 8; r++) u[r] = *(const f32x4*)(src + (size_t)r * DIM);
#pragma unroll
      for (int c = 0; c < 4; c++) {
        f16x8 h;
#pragma unroll
        for (int r = 0; r < 8; r++) h[r] = (_Float16)u[r][c];
        const int n  = bn0 + c;
        const int gi = br ^ (n & 7);
        *(f16x8*)&Bs[n * 64 + gi * 8] = h;
      }
    }
    __syncthreads();
#pragma unroll
    for (int ks = 0; ks < 2; ++ks) {
      const int gq = ks * 4 + (lane >> 4);
      f16x8 af[4], bf[4];
#pragma unroll
      for (int fm = 0; fm < 4; ++fm) {
        const int m = wm * 64 + fm * 16 + (lane & 15);
        af[fm] = *(const f16x8*)&As[m * 64 + (gq ^ (m & 7)) * 8];
      }
#pragma unroll
      for (int fn = 0; fn < 4; ++fn) {
        const int n = wn * 64 + fn * 16 + (lane & 15);
        bf[fn] = *(const f16x8*)&Bs[n * 64 + (gq ^ (n & 7)) * 8];
      }
#pragma unroll
      for (int fm = 0; fm < 4; ++fm)
#pragma unroll
        for (int fn = 0; fn < 4; ++fn)
          acc[fm][fn] = __builtin_amdgcn_mfma_f32_16x16x32_f16(af[fm], bf[fn], acc[fm][fn], 0, 0, 0);
    }
  }
  int   toks[4][4];
  float wgts[4][4];
#pragma unroll
  for (int fm = 0; fm < 4; ++fm)
#pragma unroll
    for (int r = 0; r < 4; r++) {
      const int row = mt * 128 + wm * 64 + fm * 16 + ((lane >> 4) << 2) + r;
      const int tk = idx[e * CAP + row];
      toks[fm][r] = tk;
      wgts[fm][r] = (tk < T_TOK) ? topw[tk] : 0.f;
    }
#pragma unroll
  for (int fn = 0; fn < 4; ++fn) {
    const int dcol = nt * 128 + wn * 64 + fn * 16 + (lane & 15);
    const float bb = b2[e * DIM + dcol];
#pragma unroll
    for (int fm = 0; fm < 4; ++fm)
#pragma unroll
      for (int r = 0; r < 4; r++) {
        const int tk = toks[fm][r];
        if (tk < T_TOK)
          out[(size_t)tk * DIM + dcol] = (acc[fm][fn][r] + bb) * wgts[fm][r];
      }
  }
}

// ---------------------------------------------------------------------------
extern "C" void kernel_launch(void* const* d_in, const int* in_sizes, int n_in,
                              void* d_out, int out_size, void* d_ws, size_t ws_size,
                              hipStream_t stream)
{
  const float* x  = (const float*)d_in[0];
  const float* Wr = (const float*)d_in[1];
  const float* W1 = (const float*)d_in[2];
  const float* b1 = (const float*)d_in[3];
  const float* W2 = (const float*)d_in[4];
  const float* b2 = (const float*)d_in[5];
  float* out = (float*)d_out;
  char* ws = (char*)d_ws;

  const size_t HID  = 67108864ull;  // 8*1024*4096*2 fp16
  const size_t WIMG = 67108864ull;  // shared W1/W2 image buffer
  const size_t XG   = 16777216ull;  // 8*1024*1024*2 fp16
  const size_t NEED = HID + WIMG + XG + 3 * 32768ull;

  if (ws_size >= NEED) {
    _Float16* hidden = (_Float16*)ws;
    _Float16* wimg   = (_Float16*)(ws + HID);
    _Float16* xg     = (_Float16*)(ws + HID + WIMG);
    int*   idx  = (int*)(ws + HID + WIMG + XG);
    int*   top  = idx + 8192;
    float* topw = (float*)(top + 8192);

    hipMemsetAsync(d_out, 0, (size_t)T_TOK * DIM * sizeof(float), stream);
    moe_router<<<T_TOK / 16, 256, 0, stream>>>(x, Wr, top, topw);
    moe_scan<<<1, 256, 0, stream>>>(top, idx);
    xg_pass<<<NE * 4 * 16, 256, 0, stream>>>(x, idx, xg);
    w_image<256, 16, 16, FF><<<NE * 16 * 16, 256, 0, stream>>>(W1, wimg);
    gemm1_big<<<NE * 4 * 16, 512, 0, stream>>>(xg, wimg, b1, hidden);
    w_image<128, 64, 8, DIM><<<NE * 8 * 64, 256, 0, stream>>>(W2, wimg);
    gemm2_big<<<NE * 4 * 8, 512, 0, stream>>>(hidden, wimg, b2, idx, topw, out);
  } else {
    _Float16* hidden = (_Float16*)ws;
    const size_t HID_BYTES = (size_t)NE * CAP * FF * 2;
    int*   idx  = (int*)(ws + HID_BYTES);
    int*   top  = (int*)(ws + HID_BYTES + 32768);
    float* topw = (float*)(ws + HID_BYTES + 65536);

    hipMemsetAsync(d_out, 0, (size_t)T_TOK * DIM * sizeof(float), stream);
    moe_router<<<T_TOK / 16, 256, 0, stream>>>(x, Wr, top, topw);
    moe_scan<<<1, 256, 0, stream>>>(top, idx);
    moe_gemm1<<<NE * 8 * 32, 256, 0, stream>>>(x, W1, b1, idx, hidden);
    moe_gemm2<<<NE * 8 * 8, 256, 0, stream>>>(hidden, W2, b2, idx, topw, out);
  }
}

// Round 3
// 345.388 us; speedup vs baseline: 1.1357x; 1.0397x over previous
//
#include <hip/hip_runtime.h>
#include <hip/hip_bf16.h>
#include <hip/hip_fp16.h>

typedef _Float16 f16x8 __attribute__((ext_vector_type(8)));
typedef _Float16 f16x4 __attribute__((ext_vector_type(4)));
typedef float f32x4 __attribute__((ext_vector_type(4)));

#define T_TOK 8192
#define DIM   1024
#define FF    4096
#define NE    8
#define CAP   1024

// ---------------------------------------------------------------------------
// async global->LDS 16B copy. LDS dest = wave-uniform base + lane*16 (HW);
// global src is per-lane.
// ---------------------------------------------------------------------------
__device__ __forceinline__ void cp16(_Float16* lds, const _Float16* g) {
  __builtin_amdgcn_global_load_lds(
      (const __attribute__((address_space(1))) unsigned int*)(const void*)g,
      (__attribute__((address_space(3))) unsigned int*)(void*)lds, 16, 0, 0);
}

// ---------------------------------------------------------------------------
// Router (proven): logits = x @ Wr, softmax, top-1, weight = prob of argmax
// ---------------------------------------------------------------------------
__global__ __launch_bounds__(256) void moe_router(
    const float* __restrict__ x, const float* __restrict__ Wr,
    int* __restrict__ top, float* __restrict__ topw)
{
  __shared__ float sWr[DIM * 9];
  const int tid = threadIdx.x;
  for (int i = tid; i < DIM * NE; i += 256) {
    int d = i >> 3, e = i & 7;
    sWr[d * 9 + e] = Wr[i];
  }
  __syncthreads();
  const int lane = tid & 63, w = tid >> 6;
  for (int t = 0; t < 4; ++t) {
    const int token = blockIdx.x * 16 + w * 4 + t;
    float acc[8] = {0.f, 0.f, 0.f, 0.f, 0.f, 0.f, 0.f, 0.f};
    for (int j = 0; j < 16; ++j) {
      float xv = x[(size_t)token * DIM + j * 64 + lane];
      const float* wr = &sWr[(j * 64 + lane) * 9];
#pragma unroll
      for (int e = 0; e < 8; ++e) acc[e] += xv * wr[e];
    }
#pragma unroll
    for (int e = 0; e < 8; ++e) {
#pragma unroll
      for (int off = 32; off > 0; off >>= 1)
        acc[e] += __shfl_xor(acc[e], off, 64);
    }
    if (lane == 0) {
      float m = acc[0];
#pragma unroll
      for (int e = 1; e < 8; ++e) m = fmaxf(m, acc[e]);
      float s = 0.f;
#pragma unroll
      for (int e = 0; e < 8; ++e) s += expf(acc[e] - m);
      int bi = 0; float bv = acc[0];
#pragma unroll
      for (int e = 1; e < 8; ++e) { if (acc[e] > bv) { bv = acc[e]; bi = e; } }
      top[token]  = bi;
      topw[token] = 1.0f / s;
    }
  }
}

// ---------------------------------------------------------------------------
// Order-preserving dispatch (proven)
// ---------------------------------------------------------------------------
__global__ __launch_bounds__(256) void moe_scan(
    const int* __restrict__ top, int* __restrict__ idx)
{
  __shared__ int running[8];
  __shared__ int wcnt[4][8];
  __shared__ int wpre[4][8];
  __shared__ int cbase[8];
  const int tid = threadIdx.x, lane = tid & 63, w = tid >> 6;
  for (int i = tid; i < NE * CAP; i += 256) idx[i] = T_TOK;
  if (tid < 8) running[tid] = 0;
  __syncthreads();
  for (int chunk = 0; chunk < T_TOK / 256; ++chunk) {
    const int tok = chunk * 256 + tid;
    const int e = top[tok];
    unsigned long long mymask = 0ull;
#pragma unroll
    for (int ee = 0; ee < 8; ++ee) {
      unsigned long long m = __ballot(e == ee);
      if (ee == e) mymask = m;
      if (lane == ee) wcnt[w][ee] = __builtin_popcountll(m);
    }
    const int rankw = __builtin_popcountll(mymask & ((1ull << lane) - 1ull));
    __syncthreads();
    if (tid < 8) {
      int c0 = wcnt[0][tid], c1 = wcnt[1][tid], c2 = wcnt[2][tid], c3 = wcnt[3][tid];
      wpre[0][tid] = 0; wpre[1][tid] = c0; wpre[2][tid] = c0 + c1; wpre[3][tid] = c0 + c1 + c2;
      cbase[tid] = running[tid];
      running[tid] += c0 + c1 + c2 + c3;
    }
    __syncthreads();
    const int rank = cbase[e] + wpre[w][e] + rankw;
    if (rank < CAP) idx[e * CAP + rank] = tok;
  }
}

// ---------------------------------------------------------------------------
// Gathered-x fp16 image (proven): tiles [e][mt256 4][kt 16][256 rows][8 gran],
// granule g stored at g ^ (row&7). OOB rows -> zeros.
// ---------------------------------------------------------------------------
__global__ __launch_bounds__(256) void xg_pass(
    const float* __restrict__ x, const int* __restrict__ idx,
    _Float16* __restrict__ img)
{
  const int tid = threadIdx.x, bid = blockIdx.x;
  const int kt = bid & 15, mt = (bid >> 4) & 3, e = bid >> 6;
  const int tok = idx[e * CAP + mt * 256 + tid];
  _Float16* dst = img + (size_t)((e * 4 + mt) * 16 + kt) * 16384 + (size_t)tid * 64;
  if (tok < T_TOK) {
    const f32x4* src = (const f32x4*)(x + (size_t)tok * DIM + kt * 64);
    f32x4 v[16];
#pragma unroll
    for (int i = 0; i < 16; ++i) v[i] = src[i];
#pragma unroll
    for (int g = 0; g < 8; ++g) {
      f16x8 h;
#pragma unroll
      for (int c = 0; c < 4; ++c) {
        h[c]     = (_Float16)v[2 * g][c];
        h[4 + c] = (_Float16)v[2 * g + 1][c];
      }
      *(f16x8*)(dst + ((g ^ (tid & 7)) * 8)) = h;
    }
  } else {
    f16x8 z = {};
#pragma unroll
    for (int g = 0; g < 8; ++g) *(f16x8*)(dst + g * 8) = z;
  }
}

// ---------------------------------------------------------------------------
// W fp32 [K][N] -> fp16 image tiles [n BN][k 64], granule g at g ^ (n&7)
// (proven)
// ---------------------------------------------------------------------------
template<int BN, int NKT, int NNT, int NFULL>
__global__ __launch_bounds__(256) void w_image(
    const float* __restrict__ W, _Float16* __restrict__ img)
{
  __shared__ _Float16 sT[64 * BN];
  const int tid = threadIdx.x, bid = blockIdx.x;
  const int kt = bid % NKT, nt = (bid / NKT) % NNT, e = bid / (NKT * NNT);
  const float* src = W + (size_t)e * (NKT * 64) * NFULL + (size_t)(kt * 64) * NFULL + nt * BN;
  constexpr int CPT = (64 * BN / 4) / 256;
#pragma unroll
  for (int i = 0; i < CPT; ++i) {
    const int q = i * 256 + tid;
    const int row = q / (BN / 4), c4 = q % (BN / 4);
    f32x4 u = *(const f32x4*)(src + (size_t)row * NFULL + c4 * 4);
    f16x4 h;
#pragma unroll
    for (int c = 0; c < 4; ++c) h[c] = (_Float16)u[c];
    *(f16x4*)&sT[row * BN + c4 * 4] = h;
  }
  __syncthreads();
  _Float16* dst = img + (size_t)bid * (BN * 64);
  constexpr int GPT = BN * 8 / 256;
  const int n = tid % BN, gb = (tid / BN) * GPT;
#pragma unroll
  for (int i = 0; i < GPT; ++i) {
    const int gpos = gb + i, g = gpos ^ (n & 7);
    f16x8 h;
#pragma unroll
    for (int j = 0; j < 8; ++j) h[j] = sT[(g * 8 + j) * BN + n];
    *(f16x8*)(dst + (size_t)n * 64 + gpos * 8) = h;
  }
}

// ---------------------------------------------------------------------------
// GEMM1: hidden = relu(xg @ W1img + b1). m97 structure: 128x128xBK64,
// 256 thr (4 waves 2x2), single-buffer 32KB LDS, 2 barriers/K-step,
// gload_lds staging, 3 blocks/CU. Epilogue: LDS-bounce transpose ->
// sector-aligned f16x8 stores into the hidden image.
// ---------------------------------------------------------------------------
__global__ __launch_bounds__(256, 3) void gemm1_big(
    const _Float16* __restrict__ xg, const _Float16* __restrict__ w1img,
    const float* __restrict__ b1, _Float16* __restrict__ hidden)
{
  __shared__ _Float16 As[8192];
  __shared__ _Float16 Bs[8192];
  const int tid = threadIdx.x, lane = tid & 63, w = tid >> 6;
  const int wm = w >> 1, wn = w & 1;
  const int l15 = lane & 15, l4 = lane >> 4;
  const int bid = blockIdx.x;
  // bid = mt*256 + e*32 + nt : same (e,nt) B-panel -> same bid%8 -> same XCD
  const int nt = bid & 31;          // 128-col F tile (32)
  const int e  = (bid >> 5) & 7;
  const int mt = bid >> 8;          // 128-row tile (8)

  // 128-row/col half-slices of the 256-wide image tiles (contiguous, parity-safe)
  const _Float16* aSrc = xg + ((size_t)(e * 4 + (mt >> 1)) * 16) * 16384
                         + (size_t)(mt & 1) * 8192 + w * 2048 + lane * 8;
  const _Float16* bSrc = w1img + ((size_t)(e * 16 + (nt >> 1)) * 16) * 16384
                         + (size_t)(nt & 1) * 8192 + w * 2048 + lane * 8;

  f32x4 acc[4][4];
#pragma unroll
  for (int i = 0; i < 4; ++i)
#pragma unroll
    for (int j = 0; j < 4; ++j) acc[i][j] = (f32x4){0.f, 0.f, 0.f, 0.f};

  for (int kt = 0; kt < 16; ++kt) {
    __syncthreads();
#pragma unroll
    for (int i = 0; i < 4; ++i) {
      cp16(&As[w * 2048 + i * 512], aSrc + (size_t)kt * 16384 + i * 512);
      cp16(&Bs[w * 2048 + i * 512], bSrc + (size_t)kt * 16384 + i * 512);
    }
    __syncthreads();
#pragma unroll
    for (int ks = 0; ks < 2; ++ks) {
      const int gq = ks * 4 + l4;
      f16x8 af[4], bf[4];
#pragma unroll
      for (int fm = 0; fm < 4; ++fm) {
        const int m = wm * 64 + fm * 16 + l15;
        af[fm] = *(const f16x8*)&As[m * 64 + (gq ^ (m & 7)) * 8];
      }
#pragma unroll
      for (int fn = 0; fn < 4; ++fn) {
        const int n = wn * 64 + fn * 16 + l15;
        bf[fn] = *(const f16x8*)&Bs[n * 64 + (gq ^ (n & 7)) * 8];
      }
#pragma unroll
      for (int fm = 0; fm < 4; ++fm)
#pragma unroll
        for (int fn = 0; fn < 4; ++fn)
          acc[fm][fn] = __builtin_amdgcn_mfma_f32_16x16x32_f16(af[fm], bf[fn], acc[fm][fn], 0, 0, 0);
    }
  }

  // ---- epilogue: LDS-bounce transpose, relu(acc+b1) -> hidden image ----
  __syncthreads();  // all LDS reads of the K-loop done; reuse As/Bs as scratch
  float* sw = (float*)((w < 2) ? As : Bs) + (size_t)(w & 1) * 2048;  // 8KB/wave
  const int ftile = nt * 2 + wn;                 // 0..63
  const size_t tbase = ((size_t)((e * 8 + mt) * 64) + ftile) * 8192;
  const int fbase = nt * 128 + wn * 64;
#pragma unroll
  for (int fm = 0; fm < 4; ++fm) {
    // write chunk: 16 rows (this fm) x 64 f, padded [f][17]
#pragma unroll
    for (int fn = 0; fn < 4; ++fn) {
      const int floc = fn * 16 + l15;
      const float bb = b1[e * FF + fbase + floc];
      f32x4 v;
#pragma unroll
      for (int r = 0; r < 4; ++r) v[r] = fmaxf(acc[fm][fn][r] + bb, 0.f);
      *(f32x4*)&sw[floc * 17 + l4 * 4] = v;
    }
    // read back: lane = (row p = l15, granule quad l4); g = it*4+l4 so the 4
    // lanes of a row cover one aligned 64B sector of the hidden image row.
    const int p = l15;
    const int mrow = wm * 64 + fm * 16 + p;
#pragma unroll
    for (int it = 0; it < 2; ++it) {
      const int g = it * 4 + l4;
      f16x8 h;
#pragma unroll
      for (int j = 0; j < 8; ++j) h[j] = (_Float16)sw[(g * 8 + j) * 17 + p];
      *(f16x8*)&hidden[tbase + (size_t)mrow * 64 + (g ^ (mrow & 7)) * 8] = h;
    }
  }
}

// ---------------------------------------------------------------------------
// GEMM2: out[tok] = (hidden @ W2img + b2) * topw. Same m97 structure.
// bid = nt*64 + e*8 + mt : same (e,mt) A-panel -> same bid%64 -> same XCD.
// ---------------------------------------------------------------------------
__global__ __launch_bounds__(256, 3) void gemm2_big(
    const _Float16* __restrict__ hidden, const _Float16* __restrict__ w2img,
    const float* __restrict__ b2, const int* __restrict__ idx,
    const float* __restrict__ topw, float* __restrict__ out)
{
  __shared__ _Float16 As[8192];
  __shared__ _Float16 Bs[8192];
  const int tid = threadIdx.x, lane = tid & 63, w = tid >> 6;
  const int wm = w >> 1, wn = w & 1;
  const int l15 = lane & 15, l4 = lane >> 4;
  const int bid = blockIdx.x;
  const int nt = bid >> 6;          // D tile (8)
  const int e  = (bid >> 3) & 7;
  const int mt = bid & 7;           // 128-row tile (8)

  const _Float16* aSrc = hidden + ((size_t)((e * 8 + mt) * 64)) * 8192 + w * 2048 + lane * 8;
  const _Float16* bSrc = w2img  + ((size_t)((e * 8 + nt) * 64)) * 8192 + w * 2048 + lane * 8;

  f32x4 acc[4][4];
#pragma unroll
  for (int i = 0; i < 4; ++i)
#pragma unroll
    for (int j = 0; j < 4; ++j) acc[i][j] = (f32x4){0.f, 0.f, 0.f, 0.f};

  for (int kt = 0; kt < 64; ++kt) {
    __syncthreads();
#pragma unroll
    for (int i = 0; i < 4; ++i) {
      cp16(&As[w * 2048 + i * 512], aSrc + (size_t)kt * 8192 + i * 512);
      cp16(&Bs[w * 2048 + i * 512], bSrc + (size_t)kt * 8192 + i * 512);
    }
    __syncthreads();
#pragma unroll
    for (int ks = 0; ks < 2; ++ks) {
      const int gq = ks * 4 + l4;
      f16x8 af[4], bf[4];
#pragma unroll
      for (int fm = 0; fm < 4; ++fm) {
        const int m = wm * 64 + fm * 16 + l15;
        af[fm] = *(const f16x8*)&As[m * 64 + (gq ^ (m & 7)) * 8];
      }
#pragma unroll
      for (int fn = 0; fn < 4; ++fn) {
        const int n = wn * 64 + fn * 16 + l15;
        bf[fn] = *(const f16x8*)&Bs[n * 64 + (gq ^ (n & 7)) * 8];
      }
#pragma unroll
      for (int fm = 0; fm < 4; ++fm)
#pragma unroll
        for (int fn = 0; fn < 4; ++fn)
          acc[fm][fn] = __builtin_amdgcn_mfma_f32_16x16x32_f16(af[fm], bf[fn], acc[fm][fn], 0, 0, 0);
    }
  }

  // epilogue: scatter (acc + b2) * topw to token rows
  int   toks[4][4];
  float wgts[4][4];
#pragma unroll
  for (int fm = 0; fm < 4; ++fm)
#pragma unroll
    for (int r = 0; r < 4; ++r) {
      const int row = mt * 128 + wm * 64 + fm * 16 + l4 * 4 + r;
      const int tk = idx[e * CAP + row];
      toks[fm][r] = tk;
      wgts[fm][r] = (tk < T_TOK) ? topw[tk] : 0.f;
    }
#pragma unroll
  for (int fn = 0; fn < 4; ++fn) {
    const int dcol = nt * 128 + wn * 64 + fn * 16 + l15;
    const float bb = b2[e * DIM + dcol];
#pragma unroll
    for (int fm = 0; fm < 4; ++fm)
#pragma unroll
      for (int r = 0; r < 4; ++r) {
        const int tk = toks[fm][r];
        if (tk < T_TOK)
          out[(size_t)tk * DIM + dcol] = (acc[fm][fn][r] + bb) * wgts[fm][r];
      }
  }
}

// ---------------------------------------------------------------------------
extern "C" void kernel_launch(void* const* d_in, const int* in_sizes, int n_in,
                              void* d_out, int out_size, void* d_ws, size_t ws_size,
                              hipStream_t stream)
{
  const float* x  = (const float*)d_in[0];
  const float* Wr = (const float*)d_in[1];
  const float* W1 = (const float*)d_in[2];
  const float* b1 = (const float*)d_in[3];
  const float* W2 = (const float*)d_in[4];
  const float* b2 = (const float*)d_in[5];
  float* out = (float*)d_out;
  char* ws = (char*)d_ws;

  const size_t HID  = 67108864ull;  // hidden image fp16
  const size_t WIMG = 67108864ull;  // shared W1/W2 image buffer
  const size_t XG   = 16777216ull;  // gathered-x image fp16

  _Float16* hidden = (_Float16*)ws;
  _Float16* wimg   = (_Float16*)(ws + HID);
  _Float16* xg     = (_Float16*)(ws + HID + WIMG);
  int*   idx  = (int*)(ws + HID + WIMG + XG);
  int*   top  = idx + 8192;
  float* topw = (float*)(top + 8192);

  hipMemsetAsync(d_out, 0, (size_t)T_TOK * DIM * sizeof(float), stream);
  moe_router<<<T_TOK / 16, 256, 0, stream>>>(x, Wr, top, topw);
  moe_scan<<<1, 256, 0, stream>>>(top, idx);
  xg_pass<<<NE * 4 * 16, 256, 0, stream>>>(x, idx, xg);
  w_image<256, 16, 16, FF><<<NE * 16 * 16, 256, 0, stream>>>(W1, wimg);
  gemm1_big<<<NE * 8 * 32, 256, 0, stream>>>(xg, wimg, b1, hidden);
  w_image<128, 64, 8, DIM><<<NE * 8 * 64, 256, 0, stream>>>(W2, wimg);
  gemm2_big<<<NE * 8 * 8, 256, 0, stream>>>(hidden, wimg, b2, idx, topw, out);
}

// Round 4
// 317.833 us; speedup vs baseline: 1.2341x; 1.0867x over previous
//
#include <hip/hip_runtime.h>
#include <hip/hip_bf16.h>
#include <hip/hip_fp16.h>

typedef _Float16 f16x8 __attribute__((ext_vector_type(8)));
typedef _Float16 f16x4 __attribute__((ext_vector_type(4)));
typedef float f32x4 __attribute__((ext_vector_type(4)));

#define T_TOK 8192
#define DIM   1024
#define FF    4096
#define NE    8
#define CAP   1024

// ---------------------------------------------------------------------------
// async global->LDS 16B copy. LDS dest = wave-uniform base + lane*16 (HW);
// global src is per-lane.
// ---------------------------------------------------------------------------
__device__ __forceinline__ void cp16(_Float16* lds, const _Float16* g) {
  __builtin_amdgcn_global_load_lds(
      (const __attribute__((address_space(1))) unsigned int*)(const void*)g,
      (__attribute__((address_space(3))) unsigned int*)(void*)lds, 16, 0, 0);
}

// ---------------------------------------------------------------------------
// Router (proven): logits = x @ Wr, softmax, top-1, weight = prob of argmax
// ---------------------------------------------------------------------------
__global__ __launch_bounds__(256) void moe_router(
    const float* __restrict__ x, const float* __restrict__ Wr,
    int* __restrict__ top, float* __restrict__ topw)
{
  __shared__ float sWr[DIM * 9];
  const int tid = threadIdx.x;
  for (int i = tid; i < DIM * NE; i += 256) {
    int d = i >> 3, e = i & 7;
    sWr[d * 9 + e] = Wr[i];
  }
  __syncthreads();
  const int lane = tid & 63, w = tid >> 6;
  for (int t = 0; t < 4; ++t) {
    const int token = blockIdx.x * 16 + w * 4 + t;
    float acc[8] = {0.f, 0.f, 0.f, 0.f, 0.f, 0.f, 0.f, 0.f};
    for (int j = 0; j < 16; ++j) {
      float xv = x[(size_t)token * DIM + j * 64 + lane];
      const float* wr = &sWr[(j * 64 + lane) * 9];
#pragma unroll
      for (int e = 0; e < 8; ++e) acc[e] += xv * wr[e];
    }
#pragma unroll
    for (int e = 0; e < 8; ++e) {
#pragma unroll
      for (int off = 32; off > 0; off >>= 1)
        acc[e] += __shfl_xor(acc[e], off, 64);
    }
    if (lane == 0) {
      float m = acc[0];
#pragma unroll
      for (int e = 1; e < 8; ++e) m = fmaxf(m, acc[e]);
      float s = 0.f;
#pragma unroll
      for (int e = 0; e < 8; ++e) s += expf(acc[e] - m);
      int bi = 0; float bv = acc[0];
#pragma unroll
      for (int e = 1; e < 8; ++e) { if (acc[e] > bv) { bv = acc[e]; bi = e; } }
      top[token]  = bi;
      topw[token] = 1.0f / s;
    }
  }
}

// ---------------------------------------------------------------------------
// Order-preserving dispatch: 1024 threads (16 waves), 8 chunks of 1024 tokens.
// Stable per-expert compaction, fill = T.
// ---------------------------------------------------------------------------
__global__ __launch_bounds__(1024) void moe_scan(
    const int* __restrict__ top, int* __restrict__ idx)
{
  __shared__ int running[8];
  __shared__ int wcnt[16][8];
  __shared__ int wpre[16][8];
  __shared__ int cbase[8];
  const int tid = threadIdx.x, lane = tid & 63, w = tid >> 6;
  for (int i = tid; i < NE * CAP; i += 1024) idx[i] = T_TOK;
  if (tid < 8) running[tid] = 0;
  __syncthreads();
  for (int chunk = 0; chunk < T_TOK / 1024; ++chunk) {
    const int tok = chunk * 1024 + tid;
    const int e = top[tok];
    unsigned long long mymask = 0ull;
#pragma unroll
    for (int ee = 0; ee < 8; ++ee) {
      unsigned long long m = __ballot(e == ee);
      if (ee == e) mymask = m;
      if (lane == ee) wcnt[w][ee] = __builtin_popcountll(m);
    }
    const int rankw = __builtin_popcountll(mymask & ((1ull << lane) - 1ull));
    __syncthreads();
    if (tid < 8) {
      int s = 0;
#pragma unroll
      for (int ww = 0; ww < 16; ++ww) { wpre[ww][tid] = s; s += wcnt[ww][tid]; }
      cbase[tid] = running[tid];
      running[tid] += s;
    }
    __syncthreads();
    const int rank = cbase[e] + wpre[w][e] + rankw;
    if (rank < CAP) idx[e * CAP + rank] = tok;
  }
}

// ---------------------------------------------------------------------------
// Gathered-x fp16 image (proven): tiles [e][mt256 4][kt 16][256 rows][8 gran],
// granule g stored at g ^ (row&7). OOB rows -> zeros.
// ---------------------------------------------------------------------------
__global__ __launch_bounds__(256) void xg_pass(
    const float* __restrict__ x, const int* __restrict__ idx,
    _Float16* __restrict__ img)
{
  const int tid = threadIdx.x, bid = blockIdx.x;
  const int kt = bid & 15, mt = (bid >> 4) & 3, e = bid >> 6;
  const int tok = idx[e * CAP + mt * 256 + tid];
  _Float16* dst = img + (size_t)((e * 4 + mt) * 16 + kt) * 16384 + (size_t)tid * 64;
  if (tok < T_TOK) {
    const f32x4* src = (const f32x4*)(x + (size_t)tok * DIM + kt * 64);
    f32x4 v[16];
#pragma unroll
    for (int i = 0; i < 16; ++i) v[i] = src[i];
#pragma unroll
    for (int g = 0; g < 8; ++g) {
      f16x8 h;
#pragma unroll
      for (int c = 0; c < 4; ++c) {
        h[c]     = (_Float16)v[2 * g][c];
        h[4 + c] = (_Float16)v[2 * g + 1][c];
      }
      *(f16x8*)(dst + ((g ^ (tid & 7)) * 8)) = h;
    }
  } else {
    f16x8 z = {};
#pragma unroll
    for (int g = 0; g < 8; ++g) *(f16x8*)(dst + g * 8) = z;
  }
}

// ---------------------------------------------------------------------------
// W fp32 [K][N] -> fp16 image tiles [n BN][k 64], granule g at g ^ (n&7)
// (proven)
// ---------------------------------------------------------------------------
template<int BN, int NKT, int NNT, int NFULL>
__global__ __launch_bounds__(256) void w_image(
    const float* __restrict__ W, _Float16* __restrict__ img)
{
  __shared__ _Float16 sT[64 * BN];
  const int tid = threadIdx.x, bid = blockIdx.x;
  const int kt = bid % NKT, nt = (bid / NKT) % NNT, e = bid / (NKT * NNT);
  const float* src = W + (size_t)e * (NKT * 64) * NFULL + (size_t)(kt * 64) * NFULL + nt * BN;
  constexpr int CPT = (64 * BN / 4) / 256;
#pragma unroll
  for (int i = 0; i < CPT; ++i) {
    const int q = i * 256 + tid;
    const int row = q / (BN / 4), c4 = q % (BN / 4);
    f32x4 u = *(const f32x4*)(src + (size_t)row * NFULL + c4 * 4);
    f16x4 h;
#pragma unroll
    for (int c = 0; c < 4; ++c) h[c] = (_Float16)u[c];
    *(f16x4*)&sT[row * BN + c4 * 4] = h;
  }
  __syncthreads();
  _Float16* dst = img + (size_t)bid * (BN * 64);
  constexpr int GPT = BN * 8 / 256;
  const int n = tid % BN, gb = (tid / BN) * GPT;
#pragma unroll
  for (int i = 0; i < GPT; ++i) {
    const int gpos = gb + i, g = gpos ^ (n & 7);
    f16x8 h;
#pragma unroll
    for (int j = 0; j < 8; ++j) h[j] = sT[(g * 8 + j) * BN + n];
    *(f16x8*)(dst + (size_t)n * 64 + gpos * 8) = h;
  }
}

// ---------------------------------------------------------------------------
// GEMM1: hidden = relu(xg @ W1img + b1). m97 structure: 128x128xBK64,
// 256 thr (4 waves 2x2), single-buffer 32KB LDS, gload_lds, 3 blocks/CU.
// bid = e*256 + (mt*4+(nt&3))*8 + (nt>>2): each XCD gets an 8mt x 4nt
// rectangle of one expert -> L2 working set 3MB (A 2 + B 1), fully resident.
// ---------------------------------------------------------------------------
__global__ __launch_bounds__(256, 3) void gemm1_big(
    const _Float16* __restrict__ xg, const _Float16* __restrict__ w1img,
    const float* __restrict__ b1, _Float16* __restrict__ hidden)
{
  __shared__ _Float16 As[8192];
  __shared__ _Float16 Bs[8192];
  const int tid = threadIdx.x, lane = tid & 63, w = tid >> 6;
  const int wm = w >> 1, wn = w & 1;
  const int l15 = lane & 15, l4 = lane >> 4;
  const int bid = blockIdx.x;
  const int e   = bid >> 8;
  const int low = bid & 255;
  const int nt  = ((low & 7) << 2) | ((low >> 3) & 3);  // 0..31
  const int mt  = low >> 5;                             // 0..7

  const _Float16* aSrc = xg + ((size_t)(e * 4 + (mt >> 1)) * 16) * 16384
                         + (size_t)(mt & 1) * 8192 + w * 2048 + lane * 8;
  const _Float16* bSrc = w1img + ((size_t)(e * 16 + (nt >> 1)) * 16) * 16384
                         + (size_t)(nt & 1) * 8192 + w * 2048 + lane * 8;

  f32x4 acc[4][4];
#pragma unroll
  for (int i = 0; i < 4; ++i)
#pragma unroll
    for (int j = 0; j < 4; ++j) acc[i][j] = (f32x4){0.f, 0.f, 0.f, 0.f};

  for (int kt = 0; kt < 16; ++kt) {
    __syncthreads();
#pragma unroll
    for (int i = 0; i < 4; ++i) {
      cp16(&As[w * 2048 + i * 512], aSrc + (size_t)kt * 16384 + i * 512);
      cp16(&Bs[w * 2048 + i * 512], bSrc + (size_t)kt * 16384 + i * 512);
    }
    __syncthreads();
#pragma unroll
    for (int ks = 0; ks < 2; ++ks) {
      const int gq = ks * 4 + l4;
      f16x8 af[4], bf[4];
#pragma unroll
      for (int fm = 0; fm < 4; ++fm) {
        const int m = wm * 64 + fm * 16 + l15;
        af[fm] = *(const f16x8*)&As[m * 64 + (gq ^ (m & 7)) * 8];
      }
#pragma unroll
      for (int fn = 0; fn < 4; ++fn) {
        const int n = wn * 64 + fn * 16 + l15;
        bf[fn] = *(const f16x8*)&Bs[n * 64 + (gq ^ (n & 7)) * 8];
      }
#pragma unroll
      for (int fm = 0; fm < 4; ++fm)
#pragma unroll
        for (int fn = 0; fn < 4; ++fn)
          acc[fm][fn] = __builtin_amdgcn_mfma_f32_16x16x32_f16(af[fm], bf[fn], acc[fm][fn], 0, 0, 0);
    }
  }

  // ---- epilogue: LDS-bounce transpose, relu(acc+b1) -> hidden image ----
  __syncthreads();
  float* sw = (float*)((w < 2) ? As : Bs) + (size_t)(w & 1) * 2048;  // 8KB/wave
  const int ftile = nt * 2 + wn;                 // 0..63
  const size_t tbase = ((size_t)((e * 8 + mt) * 64) + ftile) * 8192;
  const int fbase = nt * 128 + wn * 64;
#pragma unroll
  for (int fm = 0; fm < 4; ++fm) {
#pragma unroll
    for (int fn = 0; fn < 4; ++fn) {
      const int floc = fn * 16 + l15;
      const float bb = b1[e * FF + fbase + floc];
      f32x4 v;
#pragma unroll
      for (int r = 0; r < 4; ++r) v[r] = fmaxf(acc[fm][fn][r] + bb, 0.f);
      *(f32x4*)&sw[floc * 17 + l4 * 4] = v;
    }
    const int p = l15;
    const int mrow = wm * 64 + fm * 16 + p;
#pragma unroll
    for (int it = 0; it < 2; ++it) {
      const int g = it * 4 + l4;
      f16x8 h;
#pragma unroll
      for (int j = 0; j < 8; ++j) h[j] = (_Float16)sw[(g * 8 + j) * 17 + p];
      *(f16x8*)&hidden[tbase + (size_t)mrow * 64 + (g ^ (mrow & 7)) * 8] = h;
    }
  }
}

// ---------------------------------------------------------------------------
// GEMM2: out[tok] = (hidden @ W2img + b2) * topw. Same m97 structure.
// bid = (e>>2)*256 + (mt&3)*64 + nt*8 + (e&3)*2 + (mt>>2): XCD rectangle =
// 4mt x 8nt of one expert (k-synchronized streaming; tiny active L2 slice).
// ---------------------------------------------------------------------------
__global__ __launch_bounds__(256, 3) void gemm2_big(
    const _Float16* __restrict__ hidden, const _Float16* __restrict__ w2img,
    const float* __restrict__ b2, const int* __restrict__ idx,
    const float* __restrict__ topw, float* __restrict__ out)
{
  __shared__ _Float16 As[8192];
  __shared__ _Float16 Bs[8192];
  const int tid = threadIdx.x, lane = tid & 63, w = tid >> 6;
  const int wm = w >> 1, wn = w & 1;
  const int l15 = lane & 15, l4 = lane >> 4;
  const int bid = blockIdx.x;
  const int xcd  = bid & 7;
  const int slot = (bid >> 3) & 31;
  const int e    = ((bid >> 8) << 2) | (xcd >> 1);
  const int mt   = ((xcd & 1) << 2) | (slot >> 3);   // 0..7
  const int nt   = slot & 7;                         // 0..7

  const _Float16* aSrc = hidden + ((size_t)((e * 8 + mt) * 64)) * 8192 + w * 2048 + lane * 8;
  const _Float16* bSrc = w2img  + ((size_t)((e * 8 + nt) * 64)) * 8192 + w * 2048 + lane * 8;

  f32x4 acc[4][4];
#pragma unroll
  for (int i = 0; i < 4; ++i)
#pragma unroll
    for (int j = 0; j < 4; ++j) acc[i][j] = (f32x4){0.f, 0.f, 0.f, 0.f};

  for (int kt = 0; kt < 64; ++kt) {
    __syncthreads();
#pragma unroll
    for (int i = 0; i < 4; ++i) {
      cp16(&As[w * 2048 + i * 512], aSrc + (size_t)kt * 8192 + i * 512);
      cp16(&Bs[w * 2048 + i * 512], bSrc + (size_t)kt * 8192 + i * 512);
    }
    __syncthreads();
#pragma unroll
    for (int ks = 0; ks < 2; ++ks) {
      const int gq = ks * 4 + l4;
      f16x8 af[4], bf[4];
#pragma unroll
      for (int fm = 0; fm < 4; ++fm) {
        const int m = wm * 64 + fm * 16 + l15;
        af[fm] = *(const f16x8*)&As[m * 64 + (gq ^ (m & 7)) * 8];
      }
#pragma unroll
      for (int fn = 0; fn < 4; ++fn) {
        const int n = wn * 64 + fn * 16 + l15;
        bf[fn] = *(const f16x8*)&Bs[n * 64 + (gq ^ (n & 7)) * 8];
      }
#pragma unroll
      for (int fm = 0; fm < 4; ++fm)
#pragma unroll
        for (int fn = 0; fn < 4; ++fn)
          acc[fm][fn] = __builtin_amdgcn_mfma_f32_16x16x32_f16(af[fm], bf[fn], acc[fm][fn], 0, 0, 0);
    }
  }

  // epilogue: scatter (acc + b2) * topw to token rows
  int   toks[4][4];
  float wgts[4][4];
#pragma unroll
  for (int fm = 0; fm < 4; ++fm)
#pragma unroll
    for (int r = 0; r < 4; ++r) {
      const int row = mt * 128 + wm * 64 + fm * 16 + l4 * 4 + r;
      const int tk = idx[e * CAP + row];
      toks[fm][r] = tk;
      wgts[fm][r] = (tk < T_TOK) ? topw[tk] : 0.f;
    }
#pragma unroll
  for (int fn = 0; fn < 4; ++fn) {
    const int dcol = nt * 128 + wn * 64 + fn * 16 + l15;
    const float bb = b2[e * DIM + dcol];
#pragma unroll
    for (int fm = 0; fm < 4; ++fm)
#pragma unroll
      for (int r = 0; r < 4; ++r) {
        const int tk = toks[fm][r];
        if (tk < T_TOK)
          out[(size_t)tk * DIM + dcol] = (acc[fm][fn][r] + bb) * wgts[fm][r];
      }
  }
}

// ---------------------------------------------------------------------------
extern "C" void kernel_launch(void* const* d_in, const int* in_sizes, int n_in,
                              void* d_out, int out_size, void* d_ws, size_t ws_size,
                              hipStream_t stream)
{
  const float* x  = (const float*)d_in[0];
  const float* Wr = (const float*)d_in[1];
  const float* W1 = (const float*)d_in[2];
  const float* b1 = (const float*)d_in[3];
  const float* W2 = (const float*)d_in[4];
  const float* b2 = (const float*)d_in[5];
  float* out = (float*)d_out;
  char* ws = (char*)d_ws;

  const size_t HID  = 67108864ull;  // hidden image fp16
  const size_t WIMG = 67108864ull;  // shared W1/W2 image buffer
  const size_t XG   = 16777216ull;  // gathered-x image fp16

  _Float16* hidden = (_Float16*)ws;
  _Float16* wimg   = (_Float16*)(ws + HID);
  _Float16* xg     = (_Float16*)(ws + HID + WIMG);
  int*   idx  = (int*)(ws + HID + WIMG + XG);
  int*   top  = idx + 8192;
  float* topw = (float*)(top + 8192);

  hipMemsetAsync(d_out, 0, (size_t)T_TOK * DIM * sizeof(float), stream);
  moe_router<<<T_TOK / 16, 256, 0, stream>>>(x, Wr, top, topw);
  moe_scan<<<1, 1024, 0, stream>>>(top, idx);
  xg_pass<<<NE * 4 * 16, 256, 0, stream>>>(x, idx, xg);
  w_image<256, 16, 16, FF><<<NE * 16 * 16, 256, 0, stream>>>(W1, wimg);
  gemm1_big<<<NE * 8 * 32, 256, 0, stream>>>(xg, wimg, b1, hidden);
  w_image<128, 64, 8, DIM><<<NE * 8 * 64, 256, 0, stream>>>(W2, wimg);
  gemm2_big<<<NE * 8 * 8, 256, 0, stream>>>(hidden, wimg, b2, idx, topw, out);
}